// Round 8
// baseline (159.138 us; speedup 1.0000x reference)
//
#include <hip/hip_runtime.h>

// IndependentMLP: x(4096,1024), w0(1024,1,16), w1(1024,16,16), wf(1024,16,8)
// out[b,i,j] = sum_k tanh( sum_l tanh(x[b,i]*w0[i,l]) * w1[i,l,k] ) * wf[i,k,j]
//
// FUSED single kernel; block = 1024 thr = 16 waves, wave w owns i = ig*16+w.
// Stage x[bbase:+512][i0:+16] into LDS once (coalesced), then per-i tiny GEMMs
// on v_mfma_f32_16x16x16f16, TRANSPOSED so MFMA1 C/D layout == MFMA2 B layout:
//   MFMA1: A = w1^T frag, B = h1^T frag  -> D1[n=h2idx][m=batch]
//   MFMA2: A = wf^T frag, B = tanh(D1)   -> D2[j=outcol][m=batch]
// D2 lane (g<2, r) holds out[b0+r][i][4g..4g+3] -> direct float4 store.
//
// r6 evidence: fused kernel ~42.7 us but VALU-busy only ~55% -> ~19 us of
// dependency stalls: per-wave chain ds_read(120cy)->tanh->MFMA1->tanh->MFMA2
// too serial at 2-wide. THIS version runs 4 tiles per iteration, PHASE-BATCHED
// (4 ds_reads, 16 indep tanh, 4 MFMA1, 16 tanh, 4 MFMA2, 4 stores) for 4x
// independent work per wave, + v_cvt_pkrtz packing (2 ops per half4).
// NOTE (r1/r7 lesson): __builtin_amdgcn_cvt_pkrtz returns __fp16 vectors, not
// _Float16 -> build in __fp16 and __builtin_bit_cast to the MFMA operand type.
// w0/w1 pre-scaled by 2*log2e so tanh skips one multiply.
//
// Harness facts: 512 MiB d_ws poison + out poison are UNCONDITIONAL (C~=115us
// fixed, r3/r5/r6 consistent); only the ~43 us kernel region is controllable.

typedef _Float16 half4 __attribute__((ext_vector_type(4)));
typedef __fp16 fp16x2 __attribute__((ext_vector_type(2)));
typedef __fp16 fp16x4 __attribute__((ext_vector_type(4)));
typedef float f32x4 __attribute__((ext_vector_type(4)));

#define TANH_SCALE 2.885390081777927f  // 2*log2(e)
#define XPITCH 17

__device__ __forceinline__ float tanh_pre(float y) {
  // y = 2*log2e*x ; tanh(x) = 1 - 2/(exp2(y)+1); inf/0 endpoints -> +-1.
  float e = __builtin_amdgcn_exp2f(y);
  return 1.0f - 2.0f * __builtin_amdgcn_rcpf(e + 1.0f);
}

__device__ __forceinline__ half4 pack4(float a, float b, float c, float d) {
  fp16x2 lo = __builtin_amdgcn_cvt_pkrtz(a, b);
  fp16x2 hi = __builtin_amdgcn_cvt_pkrtz(c, d);
  fp16x4 v = __builtin_shufflevector(lo, hi, 0, 1, 2, 3);
  return __builtin_bit_cast(half4, v);
}

__global__ __launch_bounds__(1024, 8) void mlp_fused(const float* __restrict__ x,
                                                     const float* __restrict__ w0,
                                                     const float* __restrict__ w1,
                                                     const float* __restrict__ wf,
                                                     float* __restrict__ out) {
  __shared__ float xs[512 * XPITCH];  // 34816 B -> 2 blocks/CU

  const int tid = threadIdx.x;
  const int wid = tid >> 6;         // wave 0..15 -> i offset
  const int lane = tid & 63;
  const int g = lane >> 4;          // 0..3 (k-group)
  const int r = lane & 15;          // m / n / j slot
  const int ig = blockIdx.x & 63;   // 64 i-groups of 16
  const int bs = blockIdx.x >> 6;   // 8 batch splits of 512
  const int i = ig * 16 + wid;
  const int bbase = bs * 512;

  // ---- stage x slice into LDS: 1024 thr x 2 float4 = 512 rows x 16 cols ----
  {
    const int rr = tid >> 2;        // 0..255
    const int c4 = (tid & 3) * 4;   // 0,4,8,12
#pragma unroll
    for (int p = 0; p < 2; ++p) {
      const int row = p * 256 + rr;
      const float4 v =
          *(const float4*)(x + (size_t)(bbase + row) * 1024 + ig * 16 + c4);
      float* d = &xs[row * XPITCH + c4];
      d[0] = v.x; d[1] = v.y; d[2] = v.z; d[3] = v.w;
    }
  }

  // A1 = w1^T fragment: [row=n=r][k=4g+ii] = w1[i][4g+ii][r], pre-scaled.
  half4 aw1;
  {
    const float* w1p = w1 + i * 256 + g * 64 + r;
#pragma unroll
    for (int ii = 0; ii < 4; ++ii) aw1[ii] = (_Float16)(w1p[ii * 16] * TANH_SCALE);
  }
  // A2 = wf^T fragment: [row=j=r][k2=4g+ii] = wf[i][4g+ii][r], zero for r>=8.
  half4 awf;
  {
    const float* wfp = wf + i * 128 + g * 32 + r;
#pragma unroll
    for (int ii = 0; ii < 4; ++ii)
      awf[ii] = (r < 8) ? (_Float16)wfp[ii * 8] : (_Float16)0.0f;
  }
  // w0, pre-scaled likewise.
  float w0g[4];
  {
    const float4 v = *(const float4*)(w0 + i * 16 + g * 4);
    w0g[0] = v.x * TANH_SCALE; w0g[1] = v.y * TANH_SCALE;
    w0g[2] = v.z * TANH_SCALE; w0g[3] = v.w * TANH_SCALE;
  }

  __syncthreads();

  // Direct store base: lane (g<2, r) owns out[bbase+r][i][4g..4g+3].
  float* op = out + (size_t)(bbase + r) * 8192 + i * 8 + g * 4;
  // LDS read base: lane r reads xs[(t*16+r)*17 + wid] (broadcast across g).
  const float* xr = &xs[r * XPITCH + wid];

  const f32x4 zero = {0.f, 0.f, 0.f, 0.f};

  // 4 tiles per iteration, phase-batched for 4x independent chains per wave.
#pragma unroll
  for (int t = 0; t < 32; t += 4) {
    float xv[4];
#pragma unroll
    for (int q = 0; q < 4; ++q) xv[q] = xr[(size_t)(t + q) * 16 * XPITCH];

    half4 bh1[4];
#pragma unroll
    for (int q = 0; q < 4; ++q)
      bh1[q] = pack4(tanh_pre(xv[q] * w0g[0]), tanh_pre(xv[q] * w0g[1]),
                     tanh_pre(xv[q] * w0g[2]), tanh_pre(xv[q] * w0g[3]));

    f32x4 d1[4];
#pragma unroll
    for (int q = 0; q < 4; ++q)
      d1[q] = __builtin_amdgcn_mfma_f32_16x16x16f16(aw1, bh1[q], zero, 0, 0, 0);

    half4 bh2[4];
#pragma unroll
    for (int q = 0; q < 4; ++q)
      bh2[q] = pack4(tanh_pre(d1[q][0]), tanh_pre(d1[q][1]),
                     tanh_pre(d1[q][2]), tanh_pre(d1[q][3]));

    f32x4 d2[4];
#pragma unroll
    for (int q = 0; q < 4; ++q)
      d2[q] = __builtin_amdgcn_mfma_f32_16x16x16f16(awf, bh2[q], zero, 0, 0, 0);

    if (g < 2) {
#pragma unroll
      for (int q = 0; q < 4; ++q)
        *(f32x4*)(op + (size_t)(t + q) * 16 * 8192) = d2[q];
    }
  }
}

extern "C" void kernel_launch(void* const* d_in, const int* in_sizes, int n_in,
                              void* d_out, int out_size, void* d_ws, size_t ws_size,
                              hipStream_t stream) {
  const float* x = (const float*)d_in[0];
  const float* w0 = (const float*)d_in[1];
  const float* w1 = (const float*)d_in[2];
  const float* wf = (const float*)d_in[3];
  float* out = (float*)d_out;
  (void)d_ws; (void)ws_size;  // workspace poison is unconditional; ws unused

  mlp_fused<<<512, 1024, 0, stream>>>(x, w0, w1, wf, out);
}